// Round 4
// baseline (40.740 us; speedup 1.0000x reference)
//
#include <hip/hip_runtime.h>

// x [4096, 3072] fp32.
//   out = ( sum_d (colsum_d)^2 - sum x^4 ) / D,   colsum_d = sum_i x[i,d]^2
// Single fused kernel + 24KB memset node.
// Column sums accumulated as fixed-point int64 atomics (order-independent ->
// deterministic). Last-arriving block (counter + __threadfence) does the
// fixed-order final combine. No spin, no co-residency assumption.

#define NROWS 4096
#define NCOLS 3072
#define NC4   768                 // float4 columns
#define GBX   6                   // 128 float4-cols per block-x
#define GBY   64                  // 64-row chunks
#define NBLOCKS (GBX * GBY)       // 384
#define TPB   512                 // 128 cols x 4 row-subgroups
#define ROWS_PER 16               // 64 rows / 4 subgroups
#define SCALE_C 16777216.0        // 2^24 fixed-point for column sums
#define SCALE_Q 1048576.0         // 2^20 fixed-point for quartic sum
#define DINV (1.0 / (double)NCOLS)

// ws layout (bytes), zeroed by memset node each call:
#define WS_CELLS_OFF 0                      // ull cells[3072]  = 24576 B
#define WS_QUART_OFF (NCOLS * 8)            // ull quart
#define WS_CNT_OFF   (NCOLS * 8 + 8)        // uint counter
#define WS_ZERO_BYTES (NCOLS * 8 + 16)

__global__ __launch_bounds__(TPB) void fused_orthreg(
        const float* __restrict__ x,
        unsigned long long* __restrict__ cells,
        unsigned long long* __restrict__ quart,
        unsigned int* __restrict__ counter,
        float* __restrict__ out) {
    const int t    = threadIdx.x;
    const int tc   = t & 127;                 // col-sub 0..127
    const int rsub = t >> 7;                  // row-subgroup 0..3
    const int c4   = blockIdx.x * 128 + tc;   // 0..767
    const int r0   = blockIdx.y * 64 + rsub * ROWS_PER;
    const float4* __restrict__ x4 = (const float4*)x;

    // ---- phase 1: stream 16 float4 rows, accumulate x^2 (per col) and x^4 ----
    float sx = 0.f, sy = 0.f, sz = 0.f, sw = 0.f, q = 0.f;
    #pragma unroll
    for (int i = 0; i < ROWS_PER; ++i) {
        float4 v = x4[(size_t)(r0 + i) * NC4 + c4];
        float a = v.x * v.x, b = v.y * v.y, c = v.z * v.z, d = v.w * v.w;
        sx += a; sy += b; sz += c; sw += d;
        q = fmaf(a, a, q); q = fmaf(b, b, q); q = fmaf(c, c, q); q = fmaf(d, d, q);
    }

    __shared__ float4 part[3][128];
    __shared__ float  qs[8];
    __shared__ double dd[8];
    __shared__ int    lastflag;

    if (rsub) part[rsub - 1][tc] = make_float4(sx, sy, sz, sw);
    #pragma unroll
    for (int off = 32; off; off >>= 1) q += __shfl_down(q, off);
    if ((t & 63) == 0) qs[t >> 6] = q;
    __syncthreads();

    // ---- combine row-subgroups, emit fixed-point atomics ----
    if (rsub == 0) {
        float4 p0 = part[0][tc], p1 = part[1][tc], p2 = part[2][tc];
        double cx = ((double)sx + (double)p0.x) + ((double)p1.x + (double)p2.x);
        double cy = ((double)sy + (double)p0.y) + ((double)p1.y + (double)p2.y);
        double cz = ((double)sz + (double)p0.z) + ((double)p1.z + (double)p2.z);
        double cw = ((double)sw + (double)p0.w) + ((double)p1.w + (double)p2.w);
        atomicAdd(&cells[c4 * 4 + 0], (unsigned long long)__double2ll_rn(cx * SCALE_C));
        atomicAdd(&cells[c4 * 4 + 1], (unsigned long long)__double2ll_rn(cy * SCALE_C));
        atomicAdd(&cells[c4 * 4 + 2], (unsigned long long)__double2ll_rn(cz * SCALE_C));
        atomicAdd(&cells[c4 * 4 + 3], (unsigned long long)__double2ll_rn(cw * SCALE_C));
    }
    if (t == 0) {
        double qt = ((double)qs[0] + (double)qs[1]) + ((double)qs[2] + (double)qs[3])
                  + ((double)qs[4] + (double)qs[5]) + ((double)qs[6] + (double)qs[7]);
        atomicAdd(quart, (unsigned long long)__double2ll_rn(qt * SCALE_Q));
    }
    __syncthreads();

    // ---- last-arrival detection ----
    if (t == 0) {
        __threadfence();   // release: my atomics visible before counter bump
        unsigned int old = __hip_atomic_fetch_add(counter, 1u, __ATOMIC_ACQ_REL,
                                                  __HIP_MEMORY_SCOPE_AGENT);
        lastflag = (old == NBLOCKS - 1);
    }
    __syncthreads();
    if (!lastflag) return;

    // ---- final combine (one block, fixed order, deterministic) ----
    __threadfence();       // acquire: all blocks' atomics visible
    double acc = 0.0;
    #pragma unroll
    for (int i = 0; i < NCOLS / TPB; ++i) {   // 6 cells per thread
        unsigned long long cv = __hip_atomic_load(&cells[t + i * TPB],
                                                  __ATOMIC_RELAXED,
                                                  __HIP_MEMORY_SCOPE_AGENT);
        double cs = (double)(long long)cv * (1.0 / SCALE_C);
        acc += cs * cs;
    }
    #pragma unroll
    for (int off = 32; off; off >>= 1) acc += __shfl_down(acc, off);
    if ((t & 63) == 0) dd[t >> 6] = acc;
    __syncthreads();
    if (t == 0) {
        double total = ((dd[0] + dd[1]) + (dd[2] + dd[3]))
                     + ((dd[4] + dd[5]) + (dd[6] + dd[7]));
        unsigned long long qv = __hip_atomic_load(quart, __ATOMIC_RELAXED,
                                                  __HIP_MEMORY_SCOPE_AGENT);
        total -= (double)(long long)qv * (1.0 / SCALE_Q);
        out[0] = (float)(total * DINV);
    }
}

extern "C" void kernel_launch(void* const* d_in, const int* in_sizes, int n_in,
                              void* d_out, int out_size, void* d_ws, size_t ws_size,
                              hipStream_t stream) {
    const float* x = (const float*)d_in[0];
    float* out = (float*)d_out;
    char* ws = (char*)d_ws;
    unsigned long long* cells = (unsigned long long*)(ws + WS_CELLS_OFF);
    unsigned long long* quart = (unsigned long long*)(ws + WS_QUART_OFF);
    unsigned int*     counter = (unsigned int*)(ws + WS_CNT_OFF);

    (void)hipMemsetAsync(ws, 0, WS_ZERO_BYTES, stream);
    fused_orthreg<<<dim3(GBX, GBY), TPB, 0, stream>>>(x, cells, quart, counter, out);
}

// Round 5
// 18.820 us; speedup vs baseline: 2.1647x; 2.1647x over previous
//
#include <hip/hip_runtime.h>

// x [4096, 3072] fp32.
//   out = ( sum_d (colsum_d)^2 - sum x^4 ) / D,   colsum_d = sum_i x[i,d]^2
// k1: 768 blocks stream 48 MiB; 64-row chunks with 4-way intra-block LDS combine
//     -> col_part [64][3072] (768 KiB) + q_part[768]. No atomics, no fences.
// k2: 13 blocks (12 column-stripes + 1 quartic); last-arriving block (scoped
//     atomic counter, validated in round 2) does the fixed-order final combine.
// Kernel boundary = the only cross-XCD release/acquire (free, correct).

#define NROWS 4096
#define NCOLS 3072
#define NC4     768               // float4 columns
#define NSTRIPE 12                // 64 f4-cols per stripe
#define NCHUNK  64                // 64-row chunks
#define TPB     256
#define DINV (1.0 / (double)NCOLS)

// ws layout (bytes):
#define WS_CS_OFF  0                               // double cs_part[13]
#define WS_COL_OFF 128                             // float col_part[64][3072] = 768 KiB
#define WS_Q_OFF   (WS_COL_OFF + NCHUNK * NCOLS * 4)   // float q_part[768]
#define WS_CNT_OFF (WS_Q_OFF + NSTRIPE * NCHUNK * 4)   // uint counter

__global__ __launch_bounds__(TPB) void k1_colsq(const float* __restrict__ x,
                                                float* __restrict__ col_part,
                                                float* __restrict__ q_part,
                                                unsigned int* __restrict__ counter) {
    const int t    = threadIdx.x;
    const int tc   = t & 63;                   // f4-col within stripe
    const int rsub = t >> 6;                   // row-subgroup 0..3
    const int c4   = blockIdx.x * 64 + tc;     // 0..767
    const int r0   = blockIdx.y * 64 + rsub * 16;
    const float4* __restrict__ x4 = (const float4*)x;

    if (t == 0 && blockIdx.x == 0 && blockIdx.y == 0) *counter = 0u;  // plain store; published at kernel end

    float sx = 0.f, sy = 0.f, sz = 0.f, sw = 0.f, q = 0.f;
    #pragma unroll
    for (int i = 0; i < 16; ++i) {
        float4 v = x4[(size_t)(r0 + i) * NC4 + c4];
        float a = v.x * v.x, b = v.y * v.y, c = v.z * v.z, d = v.w * v.w;
        sx += a; sy += b; sz += c; sw += d;
        q = fmaf(a, a, q); q = fmaf(b, b, q); q = fmaf(c, c, q); q = fmaf(d, d, q);
    }

    __shared__ float4 part[3][64];
    __shared__ float  qs[4];
    if (rsub) part[rsub - 1][tc] = make_float4(sx, sy, sz, sw);
    #pragma unroll
    for (int off = 32; off; off >>= 1) q += __shfl_down(q, off);
    if ((t & 63) == 0) qs[rsub] = q;
    __syncthreads();

    if (rsub == 0) {        // wave 0: combine 4 row-subgroups, one coalesced 1KB store
        float4 p0 = part[0][tc], p1 = part[1][tc], p2 = part[2][tc];
        float4 s = make_float4((sx + p0.x) + (p1.x + p2.x),
                               (sy + p0.y) + (p1.y + p2.y),
                               (sz + p0.z) + (p1.z + p2.z),
                               (sw + p0.w) + (p1.w + p2.w));
        ((float4*)col_part)[(size_t)blockIdx.y * NC4 + c4] = s;
    }
    if (t == 0) q_part[blockIdx.y * NSTRIPE + blockIdx.x] = (qs[0] + qs[1]) + (qs[2] + qs[3]);
}

__global__ __launch_bounds__(TPB) void k2_finish(const float* __restrict__ col_part,
                                                 const float* __restrict__ q_part,
                                                 double* __restrict__ cs_part,
                                                 unsigned int* __restrict__ counter,
                                                 float* __restrict__ out) {
    const int t = threadIdx.x;
    const int b = blockIdx.x;                  // 0..12
    const int tc = t & 63, rsub = t >> 6;
    __shared__ float4 part[3][64];
    __shared__ double dsh[4];
    double partial = 0.0;

    if (b < 12) {
        // reduce 64 chunk-partials for this stripe's 64 f4-cols (4 chunks-groups x LDS)
        const float4* __restrict__ cp4 = (const float4*)col_part;
        const int c4 = b * 64 + tc;
        float4 s = make_float4(0.f, 0.f, 0.f, 0.f);
        #pragma unroll
        for (int i = 0; i < 16; ++i) {
            float4 v = cp4[(size_t)(rsub * 16 + i) * NC4 + c4];
            s.x += v.x; s.y += v.y; s.z += v.z; s.w += v.w;
        }
        if (rsub) part[rsub - 1][tc] = s;
        __syncthreads();
        if (rsub == 0) {
            float4 p0 = part[0][tc], p1 = part[1][tc], p2 = part[2][tc];
            double cx = ((double)s.x + (double)p0.x) + ((double)p1.x + (double)p2.x);
            double cy = ((double)s.y + (double)p0.y) + ((double)p1.y + (double)p2.y);
            double cz = ((double)s.z + (double)p0.z) + ((double)p1.z + (double)p2.z);
            double cw = ((double)s.w + (double)p0.w) + ((double)p1.w + (double)p2.w);
            partial = (cx * cx + cy * cy) + (cz * cz + cw * cw);
            #pragma unroll
            for (int off = 32; off; off >>= 1) partial += __shfl_down(partial, off);
        }
    } else {
        // quartic partials: 768 entries, 3 per thread
        double qd = (double)q_part[t] + (double)q_part[t + 256] + (double)q_part[t + 512];
        #pragma unroll
        for (int off = 32; off; off >>= 1) qd += __shfl_down(qd, off);
        if ((t & 63) == 0) dsh[rsub] = qd;
        __syncthreads();
        if (t == 0) partial = (dsh[0] + dsh[1]) + (dsh[2] + dsh[3]);
    }

    if (t == 0) {
        __hip_atomic_store(&cs_part[b], partial, __ATOMIC_RELEASE, __HIP_MEMORY_SCOPE_AGENT);
        unsigned int old = __hip_atomic_fetch_add(counter, 1u, __ATOMIC_ACQ_REL,
                                                  __HIP_MEMORY_SCOPE_AGENT);
        if (old == 12u) {                      // last block: fixed-order combine
            double acc = 0.0;
            #pragma unroll
            for (int i = 0; i < 12; ++i)
                acc += __hip_atomic_load(&cs_part[i], __ATOMIC_ACQUIRE,
                                         __HIP_MEMORY_SCOPE_AGENT);
            acc -= __hip_atomic_load(&cs_part[12], __ATOMIC_ACQUIRE,
                                     __HIP_MEMORY_SCOPE_AGENT);
            out[0] = (float)(acc * DINV);
        }
    }
}

extern "C" void kernel_launch(void* const* d_in, const int* in_sizes, int n_in,
                              void* d_out, int out_size, void* d_ws, size_t ws_size,
                              hipStream_t stream) {
    const float* x = (const float*)d_in[0];
    float* out = (float*)d_out;
    char* ws = (char*)d_ws;
    double* cs_part  = (double*)(ws + WS_CS_OFF);
    float*  col_part = (float*)(ws + WS_COL_OFF);
    float*  q_part   = (float*)(ws + WS_Q_OFF);
    unsigned int* counter = (unsigned int*)(ws + WS_CNT_OFF);

    k1_colsq<<<dim3(NSTRIPE, NCHUNK), TPB, 0, stream>>>(x, col_part, q_part, counter);
    k2_finish<<<13, TPB, 0, stream>>>(col_part, q_part, cs_part, counter, out);
}

// Round 6
// 17.244 us; speedup vs baseline: 2.3626x; 1.0914x over previous
//
#include <hip/hip_runtime.h>

// x [4096, 3072] fp32.
//   out = ( sum_d (colsum_d)^2 - sum x^4 ) / D,   colsum_d = sum_i x[i,d]^2
// k1: 1536 blocks (6 waves/SIMD) stream 48 MiB with non-temporal float4 loads;
//     each block: 32 f4-cols x 64 rows, 8-way LDS combine -> col_part[64][3072]
//     (768 KiB) + q_part[1536]. No atomics, no fences.
// k2: 13 blocks (12 column-stripes + 1 quartic); last-arriving block (scoped
//     atomic counter) does the fixed-order final combine.
// Kernel boundary = the only cross-XCD release/acquire (free, correct).

typedef float f4 __attribute__((ext_vector_type(4)));

#define NROWS 4096
#define NCOLS 3072
#define NC4     768               // float4 columns
#define GBX     24                // 32 f4-cols per block-x
#define NCHUNK  64                // 64-row chunks
#define NBLK1   (GBX * NCHUNK)    // 1536
#define TPB     256
#define DINV (1.0 / (double)NCOLS)

// ws layout (bytes):
#define WS_CS_OFF  0                               // double cs_part[13]
#define WS_COL_OFF 128                             // float col_part[64][3072] = 768 KiB
#define WS_Q_OFF   (WS_COL_OFF + NCHUNK * NCOLS * 4)   // float q_part[1536]
#define WS_CNT_OFF (WS_Q_OFF + NBLK1 * 4)              // uint counter

__global__ __launch_bounds__(TPB) void k1_colsq(const float* __restrict__ x,
                                                float* __restrict__ col_part,
                                                float* __restrict__ q_part,
                                                unsigned int* __restrict__ counter) {
    const int t    = threadIdx.x;
    const int tc   = t & 31;                   // f4-col within block
    const int rsub = t >> 5;                   // row-subgroup 0..7
    const int c4   = blockIdx.x * 32 + tc;     // 0..767
    const int r0   = blockIdx.y * 64 + rsub * 8;
    const f4* __restrict__ xv = (const f4*)x;

    if (t == 0 && blockIdx.x == 0 && blockIdx.y == 0) *counter = 0u;  // published at kernel end

    f4 s = (f4)(0.f);
    float q = 0.f;
    #pragma unroll
    for (int i = 0; i < 8; ++i) {
        f4 v = __builtin_nontemporal_load(&xv[(size_t)(r0 + i) * NC4 + c4]);
        f4 sq = v * v;
        s += sq;
        q = fmaf(sq.x, sq.x, q); q = fmaf(sq.y, sq.y, q);
        q = fmaf(sq.z, sq.z, q); q = fmaf(sq.w, sq.w, q);
    }

    __shared__ f4    part[7][32];
    __shared__ float qs[4];
    if (rsub) part[rsub - 1][tc] = s;
    #pragma unroll
    for (int off = 32; off; off >>= 1) q += __shfl_down(q, off);
    if ((t & 63) == 0) qs[t >> 6] = q;
    __syncthreads();

    if (rsub == 0) {        // lanes 0..31: combine 8 row-subgroups, one 512B store
        f4 p = ((part[0][tc] + part[1][tc]) + (part[2][tc] + part[3][tc]))
             + ((part[4][tc] + part[5][tc]) + (part[6][tc] + s));
        ((f4*)col_part)[(size_t)blockIdx.y * NC4 + c4] = p;
    }
    if (t == 0)
        q_part[blockIdx.y * GBX + blockIdx.x] = (qs[0] + qs[1]) + (qs[2] + qs[3]);
}

__global__ __launch_bounds__(TPB) void k2_finish(const float* __restrict__ col_part,
                                                 const float* __restrict__ q_part,
                                                 double* __restrict__ cs_part,
                                                 unsigned int* __restrict__ counter,
                                                 float* __restrict__ out) {
    const int t = threadIdx.x;
    const int b = blockIdx.x;                  // 0..12
    const int tc = t & 63, rsub = t >> 6;
    __shared__ f4 part[3][64];
    __shared__ double dsh[4];
    double partial = 0.0;

    if (b < 12) {
        // reduce 64 chunk-partials for this stripe's 64 f4-cols
        const f4* __restrict__ cp4 = (const f4*)col_part;
        const int c4 = b * 64 + tc;
        f4 s = (f4)(0.f);
        #pragma unroll
        for (int i = 0; i < 16; ++i)
            s += cp4[(size_t)(rsub * 16 + i) * NC4 + c4];
        if (rsub) part[rsub - 1][tc] = s;
        __syncthreads();
        if (rsub == 0) {
            f4 p0 = part[0][tc], p1 = part[1][tc], p2 = part[2][tc];
            double cx = ((double)s.x + (double)p0.x) + ((double)p1.x + (double)p2.x);
            double cy = ((double)s.y + (double)p0.y) + ((double)p1.y + (double)p2.y);
            double cz = ((double)s.z + (double)p0.z) + ((double)p1.z + (double)p2.z);
            double cw = ((double)s.w + (double)p0.w) + ((double)p1.w + (double)p2.w);
            partial = (cx * cx + cy * cy) + (cz * cz + cw * cw);
            #pragma unroll
            for (int off = 32; off; off >>= 1) partial += __shfl_down(partial, off);
        }
    } else {
        // quartic partials: 1536 entries, 6 per thread
        double qd = 0.0;
        #pragma unroll
        for (int i = 0; i < 6; ++i) qd += (double)q_part[t + i * TPB];
        #pragma unroll
        for (int off = 32; off; off >>= 1) qd += __shfl_down(qd, off);
        if ((t & 63) == 0) dsh[rsub] = qd;
        __syncthreads();
        if (t == 0) partial = (dsh[0] + dsh[1]) + (dsh[2] + dsh[3]);
    }

    if (t == 0) {
        __hip_atomic_store(&cs_part[b], partial, __ATOMIC_RELEASE, __HIP_MEMORY_SCOPE_AGENT);
        unsigned int old = __hip_atomic_fetch_add(counter, 1u, __ATOMIC_ACQ_REL,
                                                  __HIP_MEMORY_SCOPE_AGENT);
        if (old == 12u) {                      // last block: fixed-order combine
            double acc = 0.0;
            #pragma unroll
            for (int i = 0; i < 12; ++i)
                acc += __hip_atomic_load(&cs_part[i], __ATOMIC_ACQUIRE,
                                         __HIP_MEMORY_SCOPE_AGENT);
            acc -= __hip_atomic_load(&cs_part[12], __ATOMIC_ACQUIRE,
                                     __HIP_MEMORY_SCOPE_AGENT);
            out[0] = (float)(acc * DINV);
        }
    }
}

extern "C" void kernel_launch(void* const* d_in, const int* in_sizes, int n_in,
                              void* d_out, int out_size, void* d_ws, size_t ws_size,
                              hipStream_t stream) {
    const float* x = (const float*)d_in[0];
    float* out = (float*)d_out;
    char* ws = (char*)d_ws;
    double* cs_part  = (double*)(ws + WS_CS_OFF);
    float*  col_part = (float*)(ws + WS_COL_OFF);
    float*  q_part   = (float*)(ws + WS_Q_OFF);
    unsigned int* counter = (unsigned int*)(ws + WS_CNT_OFF);

    k1_colsq<<<dim3(GBX, NCHUNK), TPB, 0, stream>>>(x, col_part, q_part, counter);
    k2_finish<<<13, TPB, 0, stream>>>(col_part, q_part, cs_part, counter, out);
}